// Round 8
// baseline (927.999 us; speedup 1.0000x reference)
//
#include <hip/hip_runtime.h>
#include <stdint.h>

#define M_DIM 4096
#define K_DIM 4096
#define N_DIM 11008
#define KP    512              // 16B slots (8 fp16) per K row of x
#define NT    64               // K tiles of 64
#define BM    256
#define BN    128

#define SZ_OFFSET  23068672u                   // packed (s,z) u32 [32][N]
#define XW_OFFSET  25165824u
#define XW_BYTES   (4096u * 4096u * 2u)
#define WS_NEEDED  (XW_OFFSET + XW_BYTES)

typedef __attribute__((ext_vector_type(8))) _Float16 f16x8;
typedef __attribute__((ext_vector_type(2))) _Float16 f16x2;
typedef __attribute__((ext_vector_type(4))) float    f32x4;

// ---------- pre-pass 1: qweight int32 [N][K] -> k-major packed u32 qpk[K/8][N] ----------
// nibbles: [3:0]=e0 [7:4]=e2 [11:8]=e4 [15:12]=e6 [19:16]=e1 [23:20]=e3 [27:24]=e5 [31:28]=e7
__global__ void pack_qw(const int* __restrict__ qw, unsigned int* __restrict__ qpk) {
    int n   = blockIdx.x * 256 + threadIdx.x;
    int kw2 = blockIdx.y;
    if (n >= N_DIM) return;
    const int* src = qw + (size_t)n * K_DIM + kw2 * 16;
    #pragma unroll
    for (int h = 0; h < 2; ++h) {
        int4 a = *(const int4*)(src + h * 8);
        int4 b = *(const int4*)(src + h * 8 + 4);
        unsigned int w = (unsigned)a.x | ((unsigned)a.z << 4) | ((unsigned)b.x << 8) | ((unsigned)b.z << 12)
                       | ((unsigned)a.y << 16) | ((unsigned)a.w << 20) | ((unsigned)b.y << 24) | ((unsigned)b.w << 28);
        qpk[(size_t)(kw2 * 2 + h) * N_DIM + n] = w;
    }
}

// ---------- pre-pass 2: x fp32 -> fp16 slots, 16B-slot XOR-pre-swizzled ----------
__global__ void cvt_x(const float* __restrict__ x, uint4* __restrict__ xw) {
    int stride = gridDim.x * blockDim.x;
    for (int i = blockIdx.x * blockDim.x + threadIdx.x; i < M_DIM * KP; i += stride) {
        int m  = i >> 9;
        int sg = i & 511;
        const float* src = x + ((size_t)m << 12) + sg * 8;
        float4 f0 = *(const float4*)src;
        float4 f1 = *(const float4*)(src + 4);
        union { _Float16 h[8]; uint4 v; } pk;
        pk.h[0]=(_Float16)f0.x; pk.h[1]=(_Float16)f0.y;
        pk.h[2]=(_Float16)f0.z; pk.h[3]=(_Float16)f0.w;
        pk.h[4]=(_Float16)f1.x; pk.h[5]=(_Float16)f1.y;
        pk.h[6]=(_Float16)f1.z; pk.h[7]=(_Float16)f1.w;
        int dst = (sg & ~7) | ((sg & 7) ^ (m & 7));
        xw[((size_t)m << 9) + dst] = pk.v;
    }
}

// ---------- pre-pass 3: pack (scale, zero) -> u32 {f16 s | f16 z << 16} (exact) ----------
__global__ void pack_sz(const float* __restrict__ sc, const float* __restrict__ zr,
                        unsigned int* __restrict__ szp) {
    int i = blockIdx.x * 256 + threadIdx.x;
    if (i < 32 * N_DIM) {
        union { _Float16 h[2]; unsigned int u; } p;
        p.h[0] = (_Float16)sc[i];
        p.h[1] = (_Float16)zr[i];
        szp[i] = p.u;
    }
}

__device__ __forceinline__ f16x2 splat_lo(unsigned int v) {
    union { unsigned int u; f16x2 h; } r;
    r.u = __builtin_amdgcn_perm(v, v, 0x01000100u);
    return r.h;
}
__device__ __forceinline__ f16x2 splat_hi(unsigned int v) {
    union { unsigned int u; f16x2 h; } r;
    r.u = __builtin_amdgcn_perm(v, v, 0x03020302u);
    return r.h;
}

// ---------- dequant 8 nibbles -> f16x8 fragment (k-order e0..e7) ----------
__device__ __forceinline__ f16x8 dq8(unsigned int w, f16x2 s2, f16x2 z2) {
    const f16x2 k1024 = {(_Float16)1024.0f, (_Float16)1024.0f};
    union { f16x2 h; unsigned int u; } p0, p1, p2, p3;
    p0.u = 0x64006400u | (w & 0x000F000Fu);
    p1.u = 0x64006400u | ((w >> 4)  & 0x000F000Fu);
    p2.u = 0x64006400u | ((w >> 8)  & 0x000F000Fu);
    p3.u = 0x64006400u | ((w >> 12) & 0x000F000Fu);
    union { f16x2 h2[4]; f16x8 v; } r;
    r.h2[0] = (p0.h - k1024) * s2 + z2;
    r.h2[1] = (p1.h - k1024) * s2 + z2;
    r.h2[2] = (p2.h - k1024) * s2 + z2;
    r.h2[3] = (p3.h - k1024) * s2 + z2;
    return r.v;
}

#define MFMA16(d, va, vb) d = __builtin_amdgcn_mfma_f32_16x16x32_f16(va, vb, d, 0, 0, 0)

// ---------- main GEMM: 256x128 block, wave tile 128x64, A dbuf LDS, B reg-dequant ----------
__global__ __launch_bounds__(256, 2) void wq_gemm_breg(
    const uint4*        __restrict__ xw,     // fp16 [M][512] slots, pre-swizzled
    const unsigned int* __restrict__ qpk,    // packed u32 [512][N] (k-major)
    const unsigned int* __restrict__ szp,    // packed {s,z} u32 [32][N]
    const float*        __restrict__ bias,   // fp32 [N]
    float*              __restrict__ out)    // fp32 [M][N]
{
    __shared__ __align__(16) uint4 Asl[2][2048];   // [buf][row*8 + swz_slot], 64 KB

    const int tid  = threadIdx.x;
    const int lane = tid & 63;
    const int wid  = tid >> 6;
    const int wm   = wid >> 1;          // 0..1 -> 128-row half
    const int wn   = wid & 1;           // 0..1 -> 64-col half
    const int l15  = lane & 15;
    const int l4   = lane >> 4;         // 0..3

    const int m0 = blockIdx.y * BM;
    const int n0 = blockIdx.x * BN;
    const int colbase = n0 + wn * 64 + l15;

    f32x4 acc[8][4] = {};

    auto stageA = [&](int t, int b) {
        #pragma unroll
        for (int i = 0; i < 8; ++i) {
            int off16 = i * 256 + tid;          // 0..2047
            int row   = off16 >> 3;             // 0..255
            int sl    = off16 & 7;
            const uint4* gsrc = xw + (size_t)(m0 + row) * KP + t * 8 + sl;
            __builtin_amdgcn_global_load_lds(
                (const __attribute__((address_space(1))) unsigned int*)gsrc,
                (__attribute__((address_space(3))) unsigned int*)&Asl[b][off16],
                16, 0, 0);
        }
    };

    unsigned int wqA[8], wqB[8], szA[4], szB[4];

    // ---- prologue: tile-0 inputs; issue order = sz(4), gll(8), words(8) ----
    #pragma unroll
    for (int n = 0; n < 4; ++n)
        szA[n] = szp[colbase + n * 16];
    stageA(0, 0);
    #pragma unroll
    for (int n = 0; n < 4; ++n)
        #pragma unroll
        for (int ks = 0; ks < 2; ++ks)
            wqA[n * 2 + ks] = qpk[(size_t)(ks * 4 + l4) * N_DIM + colbase + n * 16];
    asm volatile("s_waitcnt vmcnt(8)" ::: "memory");   // drain sz + gll; words fly
    __builtin_amdgcn_s_barrier();

    auto tile = [&](int u, unsigned int (&wq_c)[8], unsigned int (&wq_n)[8],
                    unsigned int (&sz_c)[4], unsigned int (&sz_n)[4]) {
        const int cur = u & 1;
        const int tc  = (u + 1 < NT) ? u + 1 : NT - 1;
        const int gn  = tc >> 1;

        // 1. prefetch next sz (4 loads, oldest)
        #pragma unroll
        for (int n = 0; n < 4; ++n)
            sz_n[n] = szp[(size_t)gn * N_DIM + colbase + n * 16];
        // 2. stage next A tile (8 gll)
        stageA(tc, cur ^ 1);
        // 3. prefetch next B words (8 loads, newest)
        #pragma unroll
        for (int n = 0; n < 4; ++n)
            #pragma unroll
            for (int ks = 0; ks < 2; ++ks)
                wq_n[n * 2 + ks] = qpk[(size_t)(tc * 8 + ks * 4 + l4) * N_DIM + colbase + n * 16];

        // 4. dequant current B words into fragments
        f16x8 b[4][2];
        #pragma unroll
        for (int n = 0; n < 4; ++n) {
            f16x2 s2 = splat_lo(sz_c[n]);
            f16x2 z2 = splat_hi(sz_c[n]);
            b[n][0] = dq8(wq_c[n * 2 + 0], s2, z2);
            b[n][1] = dq8(wq_c[n * 2 + 1], s2, z2);
        }

        // 5. A fragments (XOR-deswizzled) + MFMA: 64 per wave per tile
        #pragma unroll
        for (int m = 0; m < 8; ++m) {
            int row = wm * 128 + m * 16 + l15;
            f16x8 a0 = *(const f16x8*)&Asl[cur][row * 8 + ((0 + l4) ^ (row & 7))];
            f16x8 a1 = *(const f16x8*)&Asl[cur][row * 8 + ((4 + l4) ^ (row & 7))];
            #pragma unroll
            for (int n = 0; n < 4; ++n) {
                MFMA16(acc[m][n], a0, b[n][0]);
                MFMA16(acc[m][n], a1, b[n][1]);
            }
        }

        // 6. publish next buffer: drain sz+gll (8 words stay in flight), barrier
        asm volatile("s_waitcnt vmcnt(8)" ::: "memory");
        __builtin_amdgcn_s_barrier();
    };

    for (int u = 0; u < NT; u += 2) {
        tile(u,     wqA, wqB, szA, szB);
        tile(u + 1, wqB, wqA, szB, szA);
    }

    // ---- epilogue: C/D layout col=lane&15, row=(lane>>4)*4+j ----
    #pragma unroll
    for (int n = 0; n < 4; ++n) {
        int col = n0 + wn * 64 + n * 16 + l15;
        float bv = bias[col];
        #pragma unroll
        for (int m = 0; m < 8; ++m) {
            int rbase = m0 + wm * 128 + m * 16 + l4 * 4;
            #pragma unroll
            for (int j = 0; j < 4; ++j)
                out[(size_t)(rbase + j) * N_DIM + col] = acc[m][n][j] + bv;
        }
    }
}

// ---------- fallback (round-3 proven kernel) if ws too small ----------
__global__ __launch_bounds__(256, 2) void wq_gemm_fb(
    const float* __restrict__ x, const int* __restrict__ qw,
    const float* __restrict__ scales, const float* __restrict__ zeros,
    const float* __restrict__ bias, float* __restrict__ out)
{
    __shared__ __align__(16) _Float16 As[128 * 64];
    __shared__ __align__(16) _Float16 Bs[128 * 64];
    const int tid = threadIdx.x, lane = tid & 63, wid = tid >> 6;
    const int wm = wid >> 1, wn = wid & 1, l15 = lane & 15, l4 = lane >> 4;
    const int m0 = blockIdx.y * 128, n0 = blockIdx.x * 128;
    f32x4 acc[4][4] = {};
    for (int kt = 0; kt < K_DIM / 64; ++kt) {
        const int k0 = kt * 64;
        #pragma unroll
        for (int i = 0; i < 4; ++i) {
            int ci = i * 256 + tid, row = ci >> 3, col = (ci & 7) * 8;
            const float* src = x + (size_t)(m0 + row) * K_DIM + k0 + col;
            float4 f0 = *(const float4*)src; float4 f1 = *(const float4*)(src + 4);
            union { _Float16 h[8]; uint4 v; } pk;
            pk.h[0]=(_Float16)f0.x; pk.h[1]=(_Float16)f0.y; pk.h[2]=(_Float16)f0.z; pk.h[3]=(_Float16)f0.w;
            pk.h[4]=(_Float16)f1.x; pk.h[5]=(_Float16)f1.y; pk.h[6]=(_Float16)f1.z; pk.h[7]=(_Float16)f1.w;
            *(uint4*)(As + ci * 8) = pk.v;
        }
        const int g = k0 >> 7;
        #pragma unroll
        for (int i = 0; i < 4; ++i) {
            int ci = i * 256 + tid, nl = ci >> 3, kc = (ci & 7) * 8;
            const int* qrow = qw + (size_t)(n0 + nl) * K_DIM + k0 + kc;
            int4 q0 = *(const int4*)qrow; int4 q1 = *(const int4*)(qrow + 4);
            float s = scales[(size_t)g * N_DIM + n0 + nl];
            float z = zeros [(size_t)g * N_DIM + n0 + nl];
            union { _Float16 h[8]; uint4 v; } pk;
            pk.h[0]=(_Float16)((float)q0.x*s+z); pk.h[1]=(_Float16)((float)q0.y*s+z);
            pk.h[2]=(_Float16)((float)q0.z*s+z); pk.h[3]=(_Float16)((float)q0.w*s+z);
            pk.h[4]=(_Float16)((float)q1.x*s+z); pk.h[5]=(_Float16)((float)q1.y*s+z);
            pk.h[6]=(_Float16)((float)q1.z*s+z); pk.h[7]=(_Float16)((float)q1.w*s+z);
            *(uint4*)(Bs + ci * 8) = pk.v;
        }
        __syncthreads();
        #pragma unroll
        for (int ks = 0; ks < 2; ++ks) {
            f16x8 a[4], b[4];
            #pragma unroll
            for (int m = 0; m < 4; ++m)
                a[m] = *(const f16x8*)(As + (wm*64 + m*16 + l15) * 64 + ks*32 + l4*8);
            #pragma unroll
            for (int n = 0; n < 4; ++n)
                b[n] = *(const f16x8*)(Bs + (wn*64 + n*16 + l15) * 64 + ks*32 + l4*8);
            #pragma unroll
            for (int m = 0; m < 4; ++m)
                #pragma unroll
                for (int n = 0; n < 4; ++n)
                    MFMA16(acc[m][n], a[m], b[n]);
        }
        __syncthreads();
    }
    #pragma unroll
    for (int n = 0; n < 4; ++n) {
        int col = n0 + wn * 64 + n * 16 + l15;
        float bv = bias[col];
        #pragma unroll
        for (int m = 0; m < 4; ++m) {
            int rbase = m0 + wm * 64 + m * 16 + l4 * 4;
            #pragma unroll
            for (int j = 0; j < 4; ++j)
                out[(size_t)(rbase + j) * N_DIM + col] = acc[m][n][j] + bv;
        }
    }
}

extern "C" void kernel_launch(void* const* d_in, const int* in_sizes, int n_in,
                              void* d_out, int out_size, void* d_ws, size_t ws_size,
                              hipStream_t stream) {
    const float* x  = (const float*)d_in[0];
    const int*   qw = (const int*)d_in[1];
    const float* sc = (const float*)d_in[2];
    const float* zr = (const float*)d_in[3];
    const float* bi = (const float*)d_in[4];
    float* o = (float*)d_out;

    if (ws_size >= WS_NEEDED) {
        unsigned int* qpk = (unsigned int*)d_ws;
        unsigned int* szp = (unsigned int*)((char*)d_ws + SZ_OFFSET);
        uint4* xw = (uint4*)((char*)d_ws + XW_OFFSET);
        pack_qw<<<dim3((N_DIM + 255) / 256, 256), dim3(256), 0, stream>>>(qw, qpk);
        cvt_x  <<<2048, 256, 0, stream>>>(x, xw);
        pack_sz<<<dim3((32 * N_DIM + 255) / 256), dim3(256), 0, stream>>>(sc, zr, szp);
        dim3 grid(N_DIM / BN, M_DIM / BM);   // 86 x 16
        wq_gemm_breg<<<grid, dim3(256), 0, stream>>>(
            (const uint4*)xw, qpk, szp, bi, o);
    } else {
        dim3 grid(N_DIM / 128, M_DIM / 128);
        wq_gemm_fb<<<grid, dim3(256), 0, stream>>>(x, qw, sc, zr, bi, o);
    }
}

// Round 9
// 625.649 us; speedup vs baseline: 1.4833x; 1.4833x over previous
//
#include <hip/hip_runtime.h>
#include <stdint.h>

#define M_DIM 4096
#define K_DIM 4096
#define N_DIM 11008
#define KP    512              // 16B slots (8 fp16) per K row of x
#define NT    64               // K tiles of 64
#define BM    256
#define BN    128

#define SZ_OFFSET  23068672u                   // packed (s,z) u32 [32][N]
#define XW_OFFSET  25165824u
#define XW_BYTES   (4096u * 4096u * 2u)
#define WS_NEEDED  (XW_OFFSET + XW_BYTES)

typedef __attribute__((ext_vector_type(8))) _Float16 f16x8;
typedef __attribute__((ext_vector_type(2))) _Float16 f16x2;
typedef __attribute__((ext_vector_type(4))) float    f32x4;

// ---------- pre-pass 1: qweight int32 [N][K] -> k-major packed u32 qpk[K/8][N] ----------
// nibbles: [3:0]=e0 [7:4]=e2 [11:8]=e4 [15:12]=e6 [19:16]=e1 [23:20]=e3 [27:24]=e5 [31:28]=e7
__global__ void pack_qw(const int* __restrict__ qw, unsigned int* __restrict__ qpk) {
    int n   = blockIdx.x * 256 + threadIdx.x;
    int kw2 = blockIdx.y;
    if (n >= N_DIM) return;
    const int* src = qw + (size_t)n * K_DIM + kw2 * 16;
    #pragma unroll
    for (int h = 0; h < 2; ++h) {
        int4 a = *(const int4*)(src + h * 8);
        int4 b = *(const int4*)(src + h * 8 + 4);
        unsigned int w = (unsigned)a.x | ((unsigned)a.z << 4) | ((unsigned)b.x << 8) | ((unsigned)b.z << 12)
                       | ((unsigned)a.y << 16) | ((unsigned)a.w << 20) | ((unsigned)b.y << 24) | ((unsigned)b.w << 28);
        qpk[(size_t)(kw2 * 2 + h) * N_DIM + n] = w;
    }
}

// ---------- pre-pass 2: x fp32 -> fp16 slots, 16B-slot XOR-pre-swizzled ----------
__global__ void cvt_x(const float* __restrict__ x, uint4* __restrict__ xw) {
    int stride = gridDim.x * blockDim.x;
    for (int i = blockIdx.x * blockDim.x + threadIdx.x; i < M_DIM * KP; i += stride) {
        int m  = i >> 9;
        int sg = i & 511;
        const float* src = x + ((size_t)m << 12) + sg * 8;
        float4 f0 = *(const float4*)src;
        float4 f1 = *(const float4*)(src + 4);
        union { _Float16 h[8]; uint4 v; } pk;
        pk.h[0]=(_Float16)f0.x; pk.h[1]=(_Float16)f0.y;
        pk.h[2]=(_Float16)f0.z; pk.h[3]=(_Float16)f0.w;
        pk.h[4]=(_Float16)f1.x; pk.h[5]=(_Float16)f1.y;
        pk.h[6]=(_Float16)f1.z; pk.h[7]=(_Float16)f1.w;
        int dst = (sg & ~7) | ((sg & 7) ^ (m & 7));
        xw[((size_t)m << 9) + dst] = pk.v;
    }
}

// ---------- pre-pass 3: pack (scale, zero) -> u32 {f16 s | f16 z << 16} (exact) ----------
__global__ void pack_sz(const float* __restrict__ sc, const float* __restrict__ zr,
                        unsigned int* __restrict__ szp) {
    int i = blockIdx.x * 256 + threadIdx.x;
    if (i < 32 * N_DIM) {
        union { _Float16 h[2]; unsigned int u; } p;
        p.h[0] = (_Float16)sc[i];
        p.h[1] = (_Float16)zr[i];
        szp[i] = p.u;
    }
}

__device__ __forceinline__ f16x2 splat_lo(unsigned int v) {
    union { unsigned int u; f16x2 h; } r;
    r.u = __builtin_amdgcn_perm(v, v, 0x01000100u);
    return r.h;
}
__device__ __forceinline__ f16x2 splat_hi(unsigned int v) {
    union { unsigned int u; f16x2 h; } r;
    r.u = __builtin_amdgcn_perm(v, v, 0x03020302u);
    return r.h;
}

// ---------- dequant 8 nibbles -> f16x8 fragment (k-order e0..e7) ----------
__device__ __forceinline__ f16x8 dq8(unsigned int w, f16x2 s2, f16x2 z2) {
    const f16x2 k1024 = {(_Float16)1024.0f, (_Float16)1024.0f};
    union { f16x2 h; unsigned int u; } p0, p1, p2, p3;
    p0.u = 0x64006400u | (w & 0x000F000Fu);
    p1.u = 0x64006400u | ((w >> 4)  & 0x000F000Fu);
    p2.u = 0x64006400u | ((w >> 8)  & 0x000F000Fu);
    p3.u = 0x64006400u | ((w >> 12) & 0x000F000Fu);
    union { f16x2 h2[4]; f16x8 v; } r;
    r.h2[0] = (p0.h - k1024) * s2 + z2;
    r.h2[1] = (p1.h - k1024) * s2 + z2;
    r.h2[2] = (p2.h - k1024) * s2 + z2;
    r.h2[3] = (p3.h - k1024) * s2 + z2;
    return r.v;
}

#define MFMA16(d, va, vb) d = __builtin_amdgcn_mfma_f32_16x16x32_f16(va, vb, d, 0, 0, 0)

// ---------- main GEMM: 256x128 block, wave tile 128x64, A dbuf LDS, B reg-dequant ----------
// launch_bounds(256,1): VGPR cap 512 -> no spill (r8's (256,2) capped at 128 and spilled:
// WRITE_SIZE 183->588MB of pure scratch traffic). LDS 64KB limits to 2 blocks/CU anyway.
__global__ __launch_bounds__(256, 1) void wq_gemm_breg(
    const uint4*        __restrict__ xw,     // fp16 [M][512] slots, pre-swizzled
    const unsigned int* __restrict__ qpk,    // packed u32 [512][N] (k-major)
    const unsigned int* __restrict__ szp,    // packed {s,z} u32 [32][N]
    const float*        __restrict__ bias,   // fp32 [N]
    float*              __restrict__ out)    // fp32 [M][N]
{
    __shared__ __align__(16) uint4 Asl[2][2048];   // [buf][row*8 + swz_slot], 64 KB

    const int tid  = threadIdx.x;
    const int lane = tid & 63;
    const int wid  = tid >> 6;
    const int wm   = wid >> 1;          // 0..1 -> 128-row half
    const int wn   = wid & 1;           // 0..1 -> 64-col half
    const int l15  = lane & 15;
    const int l4   = lane >> 4;         // 0..3

    const int m0 = blockIdx.y * BM;
    const int n0 = blockIdx.x * BN;
    const int colbase = n0 + wn * 64 + l15;

    f32x4 acc[8][4] = {};

    auto stageA = [&](int t, int b) {
        #pragma unroll
        for (int i = 0; i < 8; ++i) {
            int off16 = i * 256 + tid;          // 0..2047
            int row   = off16 >> 3;             // 0..255
            int sl    = off16 & 7;
            const uint4* gsrc = xw + (size_t)(m0 + row) * KP + t * 8 + sl;
            __builtin_amdgcn_global_load_lds(
                (const __attribute__((address_space(1))) unsigned int*)gsrc,
                (__attribute__((address_space(3))) unsigned int*)&Asl[b][off16],
                16, 0, 0);
        }
    };

    unsigned int wqA[8], wqB[8], szA[4], szB[4];

    // ---- prologue: tile-0 inputs; issue order = sz(4), gll(8), words(8) ----
    #pragma unroll
    for (int n = 0; n < 4; ++n)
        szA[n] = szp[colbase + n * 16];
    stageA(0, 0);
    #pragma unroll
    for (int n = 0; n < 4; ++n)
        #pragma unroll
        for (int ks = 0; ks < 2; ++ks)
            wqA[n * 2 + ks] = qpk[(size_t)(ks * 4 + l4) * N_DIM + colbase + n * 16];
    asm volatile("s_waitcnt vmcnt(8)" ::: "memory");   // drain sz + gll; words fly
    __builtin_amdgcn_s_barrier();

    auto tile = [&](int u, unsigned int (&wq_c)[8], unsigned int (&wq_n)[8],
                    unsigned int (&sz_c)[4], unsigned int (&sz_n)[4]) {
        const int cur = u & 1;
        const int tc  = (u + 1 < NT) ? u + 1 : NT - 1;
        const int gn  = tc >> 1;

        // 1. prefetch next sz (4 loads, oldest)
        #pragma unroll
        for (int n = 0; n < 4; ++n)
            sz_n[n] = szp[(size_t)gn * N_DIM + colbase + n * 16];
        // 2. stage next A tile (8 gll)
        stageA(tc, cur ^ 1);
        // 3. prefetch next B words (8 loads, newest)
        #pragma unroll
        for (int n = 0; n < 4; ++n)
            #pragma unroll
            for (int ks = 0; ks < 2; ++ks)
                wq_n[n * 2 + ks] = qpk[(size_t)(tc * 8 + ks * 4 + l4) * N_DIM + colbase + n * 16];

        // 4. dequant current B words into fragments
        f16x8 b[4][2];
        #pragma unroll
        for (int n = 0; n < 4; ++n) {
            f16x2 s2 = splat_lo(sz_c[n]);
            f16x2 z2 = splat_hi(sz_c[n]);
            b[n][0] = dq8(wq_c[n * 2 + 0], s2, z2);
            b[n][1] = dq8(wq_c[n * 2 + 1], s2, z2);
        }

        // 5. A fragments (XOR-deswizzled) + MFMA: 64 per wave per tile
        #pragma unroll
        for (int m = 0; m < 8; ++m) {
            int row = wm * 128 + m * 16 + l15;
            f16x8 a0 = *(const f16x8*)&Asl[cur][row * 8 + ((0 + l4) ^ (row & 7))];
            f16x8 a1 = *(const f16x8*)&Asl[cur][row * 8 + ((4 + l4) ^ (row & 7))];
            #pragma unroll
            for (int n = 0; n < 4; ++n) {
                MFMA16(acc[m][n], a0, b[n][0]);
                MFMA16(acc[m][n], a1, b[n][1]);
            }
        }

        // 6. publish next buffer: drain sz+gll (8 words stay in flight), barrier
        asm volatile("s_waitcnt vmcnt(8)" ::: "memory");
        __builtin_amdgcn_s_barrier();
    };

    for (int u = 0; u < NT; u += 2) {
        tile(u,     wqA, wqB, szA, szB);
        tile(u + 1, wqB, wqA, szB, szA);
    }

    // ---- epilogue: C/D layout col=lane&15, row=(lane>>4)*4+j ----
    #pragma unroll
    for (int n = 0; n < 4; ++n) {
        int col = n0 + wn * 64 + n * 16 + l15;
        float bv = bias[col];
        #pragma unroll
        for (int m = 0; m < 8; ++m) {
            int rbase = m0 + wm * 128 + m * 16 + l4 * 4;
            #pragma unroll
            for (int j = 0; j < 4; ++j)
                out[(size_t)(rbase + j) * N_DIM + col] = acc[m][n][j] + bv;
        }
    }
}

// ---------- fallback (round-3 proven kernel) if ws too small ----------
__global__ __launch_bounds__(256, 2) void wq_gemm_fb(
    const float* __restrict__ x, const int* __restrict__ qw,
    const float* __restrict__ scales, const float* __restrict__ zeros,
    const float* __restrict__ bias, float* __restrict__ out)
{
    __shared__ __align__(16) _Float16 As[128 * 64];
    __shared__ __align__(16) _Float16 Bs[128 * 64];
    const int tid = threadIdx.x, lane = tid & 63, wid = tid >> 6;
    const int wm = wid >> 1, wn = wid & 1, l15 = lane & 15, l4 = lane >> 4;
    const int m0 = blockIdx.y * 128, n0 = blockIdx.x * 128;
    f32x4 acc[4][4] = {};
    for (int kt = 0; kt < K_DIM / 64; ++kt) {
        const int k0 = kt * 64;
        #pragma unroll
        for (int i = 0; i < 4; ++i) {
            int ci = i * 256 + tid, row = ci >> 3, col = (ci & 7) * 8;
            const float* src = x + (size_t)(m0 + row) * K_DIM + k0 + col;
            float4 f0 = *(const float4*)src; float4 f1 = *(const float4*)(src + 4);
            union { _Float16 h[8]; uint4 v; } pk;
            pk.h[0]=(_Float16)f0.x; pk.h[1]=(_Float16)f0.y; pk.h[2]=(_Float16)f0.z; pk.h[3]=(_Float16)f0.w;
            pk.h[4]=(_Float16)f1.x; pk.h[5]=(_Float16)f1.y; pk.h[6]=(_Float16)f1.z; pk.h[7]=(_Float16)f1.w;
            *(uint4*)(As + ci * 8) = pk.v;
        }
        const int g = k0 >> 7;
        #pragma unroll
        for (int i = 0; i < 4; ++i) {
            int ci = i * 256 + tid, nl = ci >> 3, kc = (ci & 7) * 8;
            const int* qrow = qw + (size_t)(n0 + nl) * K_DIM + k0 + kc;
            int4 q0 = *(const int4*)qrow; int4 q1 = *(const int4*)(qrow + 4);
            float s = scales[(size_t)g * N_DIM + n0 + nl];
            float z = zeros [(size_t)g * N_DIM + n0 + nl];
            union { _Float16 h[8]; uint4 v; } pk;
            pk.h[0]=(_Float16)((float)q0.x*s+z); pk.h[1]=(_Float16)((float)q0.y*s+z);
            pk.h[2]=(_Float16)((float)q0.z*s+z); pk.h[3]=(_Float16)((float)q0.w*s+z);
            pk.h[4]=(_Float16)((float)q1.x*s+z); pk.h[5]=(_Float16)((float)q1.y*s+z);
            pk.h[6]=(_Float16)((float)q1.z*s+z); pk.h[7]=(_Float16)((float)q1.w*s+z);
            *(uint4*)(Bs + ci * 8) = pk.v;
        }
        __syncthreads();
        #pragma unroll
        for (int ks = 0; ks < 2; ++ks) {
            f16x8 a[4], b[4];
            #pragma unroll
            for (int m = 0; m < 4; ++m)
                a[m] = *(const f16x8*)(As + (wm*64 + m*16 + l15) * 64 + ks*32 + l4*8);
            #pragma unroll
            for (int n = 0; n < 4; ++n)
                b[n] = *(const f16x8*)(Bs + (wn*64 + n*16 + l15) * 64 + ks*32 + l4*8);
            #pragma unroll
            for (int m = 0; m < 4; ++m)
                #pragma unroll
                for (int n = 0; n < 4; ++n)
                    MFMA16(acc[m][n], a[m], b[n]);
        }
        __syncthreads();
    }
    #pragma unroll
    for (int n = 0; n < 4; ++n) {
        int col = n0 + wn * 64 + n * 16 + l15;
        float bv = bias[col];
        #pragma unroll
        for (int m = 0; m < 4; ++m) {
            int rbase = m0 + wm * 64 + m * 16 + l4 * 4;
            #pragma unroll
            for (int j = 0; j < 4; ++j)
                out[(size_t)(rbase + j) * N_DIM + col] = acc[m][n][j] + bv;
        }
    }
}

extern "C" void kernel_launch(void* const* d_in, const int* in_sizes, int n_in,
                              void* d_out, int out_size, void* d_ws, size_t ws_size,
                              hipStream_t stream) {
    const float* x  = (const float*)d_in[0];
    const int*   qw = (const int*)d_in[1];
    const float* sc = (const float*)d_in[2];
    const float* zr = (const float*)d_in[3];
    const float* bi = (const float*)d_in[4];
    float* o = (float*)d_out;

    if (ws_size >= WS_NEEDED) {
        unsigned int* qpk = (unsigned int*)d_ws;
        unsigned int* szp = (unsigned int*)((char*)d_ws + SZ_OFFSET);
        uint4* xw = (uint4*)((char*)d_ws + XW_OFFSET);
        pack_qw<<<dim3((N_DIM + 255) / 256, 256), dim3(256), 0, stream>>>(qw, qpk);
        cvt_x  <<<2048, 256, 0, stream>>>(x, xw);
        pack_sz<<<dim3((32 * N_DIM + 255) / 256), dim3(256), 0, stream>>>(sc, zr, szp);
        dim3 grid(N_DIM / BN, M_DIM / BM);   // 86 x 16
        wq_gemm_breg<<<grid, dim3(256), 0, stream>>>(
            (const uint4*)xw, qpk, szp, bi, o);
    } else {
        dim3 grid(N_DIM / 128, M_DIM / 128);
        wq_gemm_fb<<<grid, dim3(256), 0, stream>>>(x, qw, sc, zr, bi, o);
    }
}

// Round 10
// 484.288 us; speedup vs baseline: 1.9162x; 1.2919x over previous
//
#include <hip/hip_runtime.h>
#include <stdint.h>

#define M_DIM 4096
#define K_DIM 4096
#define N_DIM 11008
#define KP    512              // 16B slots (8 fp16) per K row
#define NT    64               // K tiles of 64

// ---- FULL path ws layout: Wf fp16 [N][K] + xw fp16 [M][K] ----
#define WF_BYTES    (11008u * 4096u * 2u)      // 90,177,536
#define XW2_OFFSET  92274688u
#define FULL_NEEDED (XW2_OFFSET + 33554432u)   // 125,829,120
// ---- MID path (round-4 proven) ws layout ----
#define XW_OFFSET  25165824u
#define WS_NEEDED  (XW_OFFSET + 33554432u)     // 58,720,256

typedef __attribute__((ext_vector_type(8))) _Float16 f16x8;
typedef __attribute__((ext_vector_type(2))) _Float16 f16x2;
typedef __attribute__((ext_vector_type(4))) float    f32x4;

#define MFMA16(d, va, vb) d = __builtin_amdgcn_mfma_f32_16x16x32_f16(va, vb, d, 0, 0, 0)

// ---------- shared pre-pass: x fp32 -> fp16 slots, XOR-pre-swizzled ----------
__global__ void cvt_x(const float* __restrict__ x, uint4* __restrict__ xw) {
    int stride = gridDim.x * blockDim.x;
    for (int i = blockIdx.x * blockDim.x + threadIdx.x; i < M_DIM * KP; i += stride) {
        int m  = i >> 9;
        int sg = i & 511;
        const float* src = x + ((size_t)m << 12) + sg * 8;
        float4 f0 = *(const float4*)src;
        float4 f1 = *(const float4*)(src + 4);
        union { _Float16 h[8]; uint4 v; } pk;
        pk.h[0]=(_Float16)f0.x; pk.h[1]=(_Float16)f0.y;
        pk.h[2]=(_Float16)f0.z; pk.h[3]=(_Float16)f0.w;
        pk.h[4]=(_Float16)f1.x; pk.h[5]=(_Float16)f1.y;
        pk.h[6]=(_Float16)f1.z; pk.h[7]=(_Float16)f1.w;
        int dst = (sg & ~7) | ((sg & 7) ^ (m & 7));
        xw[((size_t)m << 9) + dst] = pk.v;
    }
}

// ---------- FULL pre-pass: dequant W -> fp16 [N][512 slots], XOR-pre-swizzled ----------
__global__ void dq_w(const int* __restrict__ qw, const float* __restrict__ sc,
                     const float* __restrict__ zr, uint4* __restrict__ wf) {
    int stride = gridDim.x * blockDim.x;
    for (int i = blockIdx.x * blockDim.x + threadIdx.x; i < N_DIM * KP; i += stride) {
        int n  = i >> 9;
        int sg = i & 511;
        const int* src = qw + (size_t)n * K_DIM + sg * 8;
        int4 a = *(const int4*)src;
        int4 b = *(const int4*)(src + 4);
        int g = sg >> 4;                       // (sg*8)/128
        float s = sc[(size_t)g * N_DIM + n];
        float z = zr[(size_t)g * N_DIM + n];
        union { _Float16 h[8]; uint4 v; } pk;
        pk.h[0]=(_Float16)((float)a.x*s+z); pk.h[1]=(_Float16)((float)a.y*s+z);
        pk.h[2]=(_Float16)((float)a.z*s+z); pk.h[3]=(_Float16)((float)a.w*s+z);
        pk.h[4]=(_Float16)((float)b.x*s+z); pk.h[5]=(_Float16)((float)b.y*s+z);
        pk.h[6]=(_Float16)((float)b.z*s+z); pk.h[7]=(_Float16)((float)b.w*s+z);
        int dst = (sg & ~7) | ((sg & 7) ^ (n & 7));
        wf[((size_t)n << 9) + dst] = pk.v;
    }
}

// ---------- FULL main GEMM: 256x256, 8 waves, BK=64, 4-phase, counted vmcnt ----------
__global__ __launch_bounds__(512, 2) void wq_gemm_8w(
    const uint4* __restrict__ xw,    // fp16 [M][512] slots, pre-swizzled
    const uint4* __restrict__ wf,    // fp16 [N][512] slots, pre-swizzled
    const float* __restrict__ bias,
    float*       __restrict__ out)
{
    __shared__ __align__(16) uint4 Ls[2][2][2][1024];  // [buf][op][half][unit] 128KB

    const int tid  = threadIdx.x;
    const int lane = tid & 63;
    const int wid  = tid >> 6;          // 0..7
    const int wm   = wid >> 2;          // A half 0..1
    const int wn   = wid & 3;           // 0..3
    const int wbh  = wn >> 1;           // B half
    const int wbl  = wn & 1;            // 64-col slice within B half
    const int l15  = lane & 15;
    const int l4   = lane >> 4;

    // XCD-aware bijective swizzle: 688 = 8*86
    int id  = blockIdx.x;
    int swz = (id & 7) * 86 + (id >> 3);
    const int m0 = (swz & 15) * 256;    // 16 m-blocks
    const int n0 = (swz >> 4) * 256;    // 43 n-blocks

    f32x4 acc[8][4] = {};

    auto stage = [&](int t, int buf, int op, int half) {
        const uint4* base = op ? (wf + (size_t)n0 * KP) : (xw + (size_t)m0 * KP);
        #pragma unroll
        for (int i = 0; i < 2; ++i) {
            int off = i * 512 + tid;            // 0..1023
            int row = off >> 3, sl = off & 7;
            const uint4* g = base + (size_t)(half * 128 + row) * KP + t * 8 + sl;
            __builtin_amdgcn_global_load_lds(
                (const __attribute__((address_space(1))) unsigned int*)g,
                (__attribute__((address_space(3))) unsigned int*)&Ls[buf][op][half][off],
                16, 0, 0);
        }
    };

    // prologue: fully stage tile 0 (8 gll)
    stage(0, 0, 0, 0); stage(0, 0, 0, 1); stage(0, 0, 1, 0); stage(0, 0, 1, 1);

    for (int u = 0; u < NT; ++u) {
        const int cur = u & 1, nxt = cur ^ 1;
        const int tc  = (u + 1 < NT) ? u + 1 : NT - 1;
        const uint4* Ab = &Ls[cur][0][wm][0];
        const uint4* Bb = &Ls[cur][1][wbh][0];

        f16x8 a[4][2], b[4][2];

        // ---- phase 0: stage A0(t+1); publish tile t; a[0..3], b[0..1]; 16 MFMA ----
        stage(tc, nxt, 0, 0);
        asm volatile("s_waitcnt vmcnt(2)" ::: "memory");  // tile-t halves landed; 2 newest fly
        __builtin_amdgcn_s_barrier();
        #pragma unroll
        for (int mf = 0; mf < 4; ++mf) {
            int r = mf * 16 + l15;
            a[mf][0] = *(const f16x8*)(Ab + r * 8 + ((0 + l4) ^ (r & 7)));
            a[mf][1] = *(const f16x8*)(Ab + r * 8 + ((4 + l4) ^ (r & 7)));
        }
        #pragma unroll
        for (int nf = 0; nf < 2; ++nf) {
            int r = wbl * 64 + nf * 16 + l15;
            b[nf][0] = *(const f16x8*)(Bb + r * 8 + ((0 + l4) ^ (r & 7)));
            b[nf][1] = *(const f16x8*)(Bb + r * 8 + ((4 + l4) ^ (r & 7)));
        }
        __builtin_amdgcn_s_setprio(1);
        #pragma unroll
        for (int mf = 0; mf < 4; ++mf)
            #pragma unroll
            for (int nf = 0; nf < 2; ++nf) {
                MFMA16(acc[mf][nf], a[mf][0], b[nf][0]);
                MFMA16(acc[mf][nf], a[mf][1], b[nf][1]);
            }
        __builtin_amdgcn_s_setprio(0);

        // ---- phase 1: stage A1(t+1); b[2..3]; 16 MFMA ----
        stage(tc, nxt, 0, 1);
        #pragma unroll
        for (int nf = 2; nf < 4; ++nf) {
            int r = wbl * 64 + nf * 16 + l15;
            b[nf][0] = *(const f16x8*)(Bb + r * 8 + ((0 + l4) ^ (r & 7)));
            b[nf][1] = *(const f16x8*)(Bb + r * 8 + ((4 + l4) ^ (r & 7)));
        }
        __builtin_amdgcn_s_setprio(1);
        #pragma unroll
        for (int mf = 0; mf < 4; ++mf)
            #pragma unroll
            for (int nf = 2; nf < 4; ++nf) {
                MFMA16(acc[mf][nf], a[mf][0], b[nf][0]);
                MFMA16(acc[mf][nf], a[mf][1], b[nf][1]);
            }
        __builtin_amdgcn_s_setprio(0);

        // ---- phase 2: stage B0(t+1); a[4..7]; 16 MFMA ----
        stage(tc, nxt, 1, 0);
        #pragma unroll
        for (int mf = 0; mf < 4; ++mf) {
            int r = (mf + 4) * 16 + l15;
            a[mf][0] = *(const f16x8*)(Ab + r * 8 + ((0 + l4) ^ (r & 7)));
            a[mf][1] = *(const f16x8*)(Ab + r * 8 + ((4 + l4) ^ (r & 7)));
        }
        __builtin_amdgcn_s_setprio(1);
        #pragma unroll
        for (int mf = 0; mf < 4; ++mf)
            #pragma unroll
            for (int nf = 2; nf < 4; ++nf) {
                MFMA16(acc[mf + 4][nf], a[mf][0], b[nf][0]);
                MFMA16(acc[mf + 4][nf], a[mf][1], b[nf][1]);
            }
        __builtin_amdgcn_s_setprio(0);

        // ---- phase 3: stage B1(t+1); 16 MFMA ----
        stage(tc, nxt, 1, 1);
        __builtin_amdgcn_s_setprio(1);
        #pragma unroll
        for (int mf = 0; mf < 4; ++mf)
            #pragma unroll
            for (int nf = 0; nf < 2; ++nf) {
                MFMA16(acc[mf + 4][nf], a[mf][0], b[nf][0]);
                MFMA16(acc[mf + 4][nf], a[mf][1], b[nf][1]);
            }
        __builtin_amdgcn_s_setprio(0);
    }

    asm volatile("s_waitcnt vmcnt(0)" ::: "memory");   // drain tail gll before exit

    // ---- epilogue ----
    #pragma unroll
    for (int nf = 0; nf < 4; ++nf) {
        int col = n0 + wbh * 128 + wbl * 64 + nf * 16 + l15;
        float bv = bias[col];
        #pragma unroll
        for (int mf = 0; mf < 8; ++mf) {
            int rbase = m0 + wm * 128 + mf * 16 + l4 * 4;
            #pragma unroll
            for (int j = 0; j < 4; ++j)
                out[(size_t)(rbase + j) * N_DIM + col] = acc[mf][nf][j] + bv;
        }
    }
}

// ================= MID path (round-4 proven, 471 us) =================
__global__ void pack_qw(const int* __restrict__ qw, unsigned int* __restrict__ qp) {
    int stride = gridDim.x * blockDim.x;
    for (int i = blockIdx.x * blockDim.x + threadIdx.x; i < N_DIM * KP; i += stride) {
        const int* src = qw + (size_t)i * 8;
        int4 a = *(const int4*)src;
        int4 b = *(const int4*)(src + 4);
        unsigned int w = (unsigned)a.x | ((unsigned)a.z << 4) | ((unsigned)b.x << 8) | ((unsigned)b.z << 12)
                       | ((unsigned)a.y << 16) | ((unsigned)a.w << 20) | ((unsigned)b.y << 24) | ((unsigned)b.w << 28);
        qp[i] = w;
    }
}

__device__ __forceinline__ uint4 dq8m(unsigned int w, f16x2 s2, f16x2 z2) {
    const f16x2 k1024 = {(_Float16)1024.0f, (_Float16)1024.0f};
    union { f16x2 h; unsigned int u; } p0, p1, p2, p3;
    p0.u = 0x64006400u | (w & 0x000F000Fu);
    p1.u = 0x64006400u | ((w >> 4)  & 0x000F000Fu);
    p2.u = 0x64006400u | ((w >> 8)  & 0x000F000Fu);
    p3.u = 0x64006400u | ((w >> 12) & 0x000F000Fu);
    union { f16x2 h2[4]; uint4 v; } r;
    r.h2[0] = (p0.h - k1024) * s2 + z2;
    r.h2[1] = (p1.h - k1024) * s2 + z2;
    r.h2[2] = (p2.h - k1024) * s2 + z2;
    r.h2[3] = (p3.h - k1024) * s2 + z2;
    return r.v;
}

__global__ __launch_bounds__(256, 3) void wq_gemm_packed(
    const uint4*  __restrict__ xw, const uint4* __restrict__ qp4,
    const float*  __restrict__ scales, const float* __restrict__ zeros,
    const float*  __restrict__ bias, float* __restrict__ out)
{
    __shared__ __align__(16) unsigned short As[128 * 64];
    __shared__ __align__(16) unsigned short Bs[128 * 64];
    const int tid = threadIdx.x, lane = tid & 63, wid = tid >> 6;
    const int wm = wid >> 1, wn = wid & 1, l15 = lane & 15, l4 = lane >> 4;
    const int m0 = blockIdx.y * 128, n0 = blockIdx.x * 128;
    const int brow = tid >> 1, bhalf = tid & 1;
    f32x4 acc[4][4] = {};
    for (int g = 0; g < 32; ++g) {
        float s = scales[(size_t)g * N_DIM + n0 + brow];
        float z = zeros [(size_t)g * N_DIM + n0 + brow];
        f16x2 s2 = {(_Float16)s, (_Float16)s};
        f16x2 z2 = {(_Float16)z, (_Float16)z};
        #pragma unroll
        for (int half = 0; half < 2; ++half) {
            const int kt = g * 2 + half;
            #pragma unroll
            for (int i = 0; i < 4; ++i) {
                int off16 = i * 256 + tid;
                int row = off16 >> 3, sl = off16 & 7;
                const uint4* gsrc = xw + (size_t)(m0 + row) * KP + kt * 8 + sl;
                __builtin_amdgcn_global_load_lds(
                    (const __attribute__((address_space(1))) unsigned int*)gsrc,
                    (__attribute__((address_space(3))) unsigned int*)((char*)As + off16 * 16),
                    16, 0, 0);
            }
            uint4 qword = qp4[(size_t)(n0 + brow) * 128 + kt * 2 + bhalf];
            #pragma unroll
            for (int j = 0; j < 4; ++j) {
                unsigned int w = (j == 0) ? qword.x : (j == 1) ? qword.y : (j == 2) ? qword.z : qword.w;
                int sl = (bhalf * 4 + j) ^ (brow & 7);
                *(uint4*)((char*)Bs + brow * 128 + sl * 16) = dq8m(w, s2, z2);
            }
            __syncthreads();
            #pragma unroll
            for (int ks = 0; ks < 2; ++ks) {
                f16x8 a[4], b[4];
                #pragma unroll
                for (int m = 0; m < 4; ++m) {
                    int row = wm * 64 + m * 16 + l15;
                    int sl  = (ks * 4 + l4) ^ (row & 7);
                    a[m] = *(const f16x8*)((char*)As + row * 128 + sl * 16);
                }
                #pragma unroll
                for (int n = 0; n < 4; ++n) {
                    int row = wn * 64 + n * 16 + l15;
                    int sl  = (ks * 4 + l4) ^ (row & 7);
                    b[n] = *(const f16x8*)((char*)Bs + row * 128 + sl * 16);
                }
                #pragma unroll
                for (int m = 0; m < 4; ++m)
                    #pragma unroll
                    for (int n = 0; n < 4; ++n)
                        MFMA16(acc[m][n], a[m], b[n]);
            }
            __syncthreads();
        }
    }
    #pragma unroll
    for (int n = 0; n < 4; ++n) {
        int col = n0 + wn * 64 + n * 16 + l15;
        float bv = bias[col];
        #pragma unroll
        for (int m = 0; m < 4; ++m) {
            int rbase = m0 + wm * 64 + m * 16 + l4 * 4;
            #pragma unroll
            for (int j = 0; j < 4; ++j)
                out[(size_t)(rbase + j) * N_DIM + col] = acc[m][n][j] + bv;
        }
    }
}

extern "C" void kernel_launch(void* const* d_in, const int* in_sizes, int n_in,
                              void* d_out, int out_size, void* d_ws, size_t ws_size,
                              hipStream_t stream) {
    const float* x  = (const float*)d_in[0];
    const int*   qw = (const int*)d_in[1];
    const float* sc = (const float*)d_in[2];
    const float* zr = (const float*)d_in[3];
    const float* bi = (const float*)d_in[4];
    float* o = (float*)d_out;

    if (ws_size >= FULL_NEEDED) {
        uint4* wf = (uint4*)d_ws;
        uint4* xw = (uint4*)((char*)d_ws + XW2_OFFSET);
        dq_w  <<<2048, 256, 0, stream>>>(qw, sc, zr, wf);
        cvt_x <<<2048, 256, 0, stream>>>(x, xw);
        wq_gemm_8w<<<dim3(688), dim3(512), 0, stream>>>(xw, wf, bi, o);
    } else {
        unsigned int* qp = (unsigned int*)d_ws;
        uint4* xw = (uint4*)((char*)d_ws + XW_OFFSET);
        pack_qw<<<2048, 256, 0, stream>>>(qw, qp);
        cvt_x  <<<2048, 256, 0, stream>>>(x, xw);
        dim3 grid(N_DIM / 128, M_DIM / 128);
        wq_gemm_packed<<<grid, dim3(256), 0, stream>>>((const uint4*)xw, (const uint4*)qp, sc, zr, bi, o);
    }
}

// Round 11
// 433.640 us; speedup vs baseline: 2.1400x; 1.1168x over previous
//
#include <hip/hip_runtime.h>
#include <stdint.h>

#define M_DIM 4096
#define K_DIM 4096
#define N_DIM 11008
#define KP    512              // 16B slots (8 fp16) per K row
#define NT    64               // K tiles of 64

// ---- FULL path ws layout: Wf fp16 [N][K] + xw fp16 [M][K] ----
#define XW2_OFFSET  92274688u
#define FULL_NEEDED (XW2_OFFSET + 33554432u)   // 125,829,120
// ---- MID path (round-4 proven) ws layout ----
#define XW_OFFSET  25165824u
#define WS_NEEDED  (XW_OFFSET + 33554432u)     // 58,720,256

typedef __attribute__((ext_vector_type(8))) _Float16 f16x8;
typedef __attribute__((ext_vector_type(2))) _Float16 f16x2;
typedef __attribute__((ext_vector_type(4))) float    f32x4;

#define MFMA16(d, va, vb) d = __builtin_amdgcn_mfma_f32_16x16x32_f16(va, vb, d, 0, 0, 0)

// ---------- pre-pass: x fp32 -> fp16 slots, XOR-pre-swizzled ----------
__global__ void cvt_x(const float* __restrict__ x, uint4* __restrict__ xw) {
    int stride = gridDim.x * blockDim.x;
    for (int i = blockIdx.x * blockDim.x + threadIdx.x; i < M_DIM * KP; i += stride) {
        int m  = i >> 9;
        int sg = i & 511;
        const float* src = x + ((size_t)m << 12) + sg * 8;
        float4 f0 = *(const float4*)src;
        float4 f1 = *(const float4*)(src + 4);
        union { _Float16 h[8]; uint4 v; } pk;
        pk.h[0]=(_Float16)f0.x; pk.h[1]=(_Float16)f0.y;
        pk.h[2]=(_Float16)f0.z; pk.h[3]=(_Float16)f0.w;
        pk.h[4]=(_Float16)f1.x; pk.h[5]=(_Float16)f1.y;
        pk.h[6]=(_Float16)f1.z; pk.h[7]=(_Float16)f1.w;
        int dst = (sg & ~7) | ((sg & 7) ^ (m & 7));
        xw[((size_t)m << 9) + dst] = pk.v;
    }
}

// ---------- pre-pass: dequant W -> fp16 [N][512 slots], XOR-pre-swizzled ----------
__global__ void dq_w(const int* __restrict__ qw, const float* __restrict__ sc,
                     const float* __restrict__ zr, uint4* __restrict__ wf) {
    int stride = gridDim.x * blockDim.x;
    for (int i = blockIdx.x * blockDim.x + threadIdx.x; i < N_DIM * KP; i += stride) {
        int n  = i >> 9;
        int sg = i & 511;
        const int* src = qw + (size_t)n * K_DIM + sg * 8;
        int4 a = *(const int4*)src;
        int4 b = *(const int4*)(src + 4);
        int g = sg >> 4;
        float s = sc[(size_t)g * N_DIM + n];
        float z = zr[(size_t)g * N_DIM + n];
        union { _Float16 h[8]; uint4 v; } pk;
        pk.h[0]=(_Float16)((float)a.x*s+z); pk.h[1]=(_Float16)((float)a.y*s+z);
        pk.h[2]=(_Float16)((float)a.z*s+z); pk.h[3]=(_Float16)((float)a.w*s+z);
        pk.h[4]=(_Float16)((float)b.x*s+z); pk.h[5]=(_Float16)((float)b.y*s+z);
        pk.h[6]=(_Float16)((float)b.z*s+z); pk.h[7]=(_Float16)((float)b.w*s+z);
        int dst = (sg & ~7) | ((sg & 7) ^ (n & 7));
        wf[((size_t)n << 9) + dst] = pk.v;
    }
}

// ---------- FULL main GEMM: 256x256, 8 waves, 8-phase schedule, counted vmcnt ----------
__global__ __launch_bounds__(512, 2) void wq_gemm_8ph(
    const uint4* __restrict__ xw,    // fp16 [M][512] slots, pre-swizzled
    const uint4* __restrict__ wf,    // fp16 [N][512] slots, pre-swizzled
    const float* __restrict__ bias,
    float*       __restrict__ out)
{
    __shared__ __align__(16) uint4 Ls[2][2][2][1024];  // [buf][op][half][unit] 128KB

    const int tid  = threadIdx.x;
    const int lane = tid & 63;
    const int wid  = tid >> 6;          // 0..7
    const int wm   = wid >> 2;          // A half 0..1
    const int wn   = wid & 3;
    const int wbh  = wn >> 1;           // B half
    const int wbl  = wn & 1;            // 64-col slice within B half
    const int l15  = lane & 15;
    const int l4   = lane >> 4;

    // XCD-aware bijective swizzle: 688 = 8*86
    int id  = blockIdx.x;
    int swz = (id & 7) * 86 + (id >> 3);
    const int m0 = (swz & 15) * 256;    // 16 m-blocks
    const int n0 = (swz >> 4) * 256;    // 43 n-blocks

    f32x4 acc[8][4] = {};

    auto stage = [&](int t, int buf, int op, int half) {
        const uint4* base = op ? (wf + (size_t)n0 * KP) : (xw + (size_t)m0 * KP);
        #pragma unroll
        for (int i = 0; i < 2; ++i) {
            int off = i * 512 + tid;            // 0..1023
            int row = off >> 3, sl = off & 7;
            const uint4* g = base + (size_t)(half * 128 + row) * KP + t * 8 + sl;
            __builtin_amdgcn_global_load_lds(
                (const __attribute__((address_space(1))) unsigned int*)g,
                (__attribute__((address_space(3))) unsigned int*)&Ls[buf][op][half][off],
                16, 0, 0);
        }
    };

    f16x8 a[4][2], b[4][2];
    auto lda = [&](int buf, int mf4, int mbase) {   // 8 ds_reads: a[0..3] rows mbase+..
        const uint4* Ab = &Ls[buf][0][wm][0];
        #pragma unroll
        for (int mf = 0; mf < 4; ++mf) {
            int r = mbase + mf * 16 + l15;
            a[mf][0] = *(const f16x8*)(Ab + r * 8 + ((0 + l4) ^ (r & 7)));
            a[mf][1] = *(const f16x8*)(Ab + r * 8 + ((4 + l4) ^ (r & 7)));
        }
        (void)mf4;
    };
    auto ldb = [&](int buf, int nf0) {              // 4 ds_reads: b[nf0..nf0+1]
        const uint4* Bb = &Ls[buf][1][wbh][0];
        #pragma unroll
        for (int nf = 0; nf < 2; ++nf) {
            int r = wbl * 64 + (nf0 + nf) * 16 + l15;
            b[nf0 + nf][0] = *(const f16x8*)(Bb + r * 8 + ((0 + l4) ^ (r & 7)));
            b[nf0 + nf][1] = *(const f16x8*)(Bb + r * 8 + ((4 + l4) ^ (r & 7)));
        }
    };

#define QUAD(MB, NB)                                                   \
    __builtin_amdgcn_s_setprio(1);                                     \
    _Pragma("unroll")                                                  \
    for (int mf = 0; mf < 4; ++mf)                                     \
        _Pragma("unroll")                                              \
        for (int nf = 0; nf < 2; ++nf) {                               \
            MFMA16(acc[MB + mf][NB + nf], a[mf][0], b[NB + nf][0]);    \
            MFMA16(acc[MB + mf][NB + nf], a[mf][1], b[NB + nf][1]);    \
        }                                                              \
    __builtin_amdgcn_s_setprio(0);

#define BAR() __builtin_amdgcn_s_barrier()
#define VM2() asm volatile("s_waitcnt vmcnt(2)" ::: "memory")

    // ---- prologue: T0 all 4 halves + T1.A0; drain T0, leave T1.A0 flying ----
    stage(0, 0, 0, 0); stage(0, 0, 0, 1); stage(0, 0, 1, 0); stage(0, 0, 1, 1);
    stage(1, 1, 0, 0);
    VM2();
    BAR();

    for (int it = 0; it < NT / 2; ++it) {
        const int T  = 2 * it;
        const int t2 = (T + 2 < NT) ? T + 2 : NT - 1;
        const int t3 = (T + 3 < NT) ? T + 3 : NT - 1;

        // p0: reads a(rows 0-63)+b(0-1) of buf0; stage T+1.A1
        lda(0, 0, 0); ldb(0, 0);
        stage(T + 1, 1, 0, 1);
        BAR(); QUAD(0, 0); BAR();

        // p1: reads b(2-3); stage T+1.B0
        ldb(0, 2);
        stage(T + 1, 1, 1, 0);
        BAR(); QUAD(0, 2); BAR();

        // p2: reads a(rows 64-127); stage T+1.B1
        lda(0, 0, 64);
        stage(T + 1, 1, 1, 1);
        BAR(); QUAD(4, 2); BAR();

        // p3: no reads; stage T+2.A0; vmcnt(2) drains all T+1 halves
        stage(t2, 0, 0, 0);
        BAR(); QUAD(4, 0); VM2(); BAR();

        // p4: reads buf1 a(0-63)+b(0-1); stage T+2.A1
        lda(1, 0, 0); ldb(1, 0);
        stage(t2, 0, 0, 1);
        BAR(); QUAD(0, 0); BAR();

        // p5: reads b(2-3); stage T+2.B0
        ldb(1, 2);
        stage(t2, 0, 1, 0);
        BAR(); QUAD(0, 2); BAR();

        // p6: reads a(64-127); stage T+2.B1
        lda(1, 0, 64);
        stage(t2, 0, 1, 1);
        BAR(); QUAD(4, 2); BAR();

        // p7: no reads; stage T+3.A0; vmcnt(2) drains all T+2 halves
        stage(t3, 1, 0, 0);
        BAR(); QUAD(4, 0); VM2(); BAR();
    }

    asm volatile("s_waitcnt vmcnt(0)" ::: "memory");   // drain tail gll

    // ---- epilogue ----
    #pragma unroll
    for (int nf = 0; nf < 4; ++nf) {
        int col = n0 + wbh * 128 + wbl * 64 + nf * 16 + l15;
        float bv = bias[col];
        #pragma unroll
        for (int mf = 0; mf < 8; ++mf) {
            int rbase = m0 + wm * 128 + mf * 16 + l4 * 4;
            #pragma unroll
            for (int j = 0; j < 4; ++j)
                out[(size_t)(rbase + j) * N_DIM + col] = acc[mf][nf][j] + bv;
        }
    }
#undef QUAD
#undef BAR
#undef VM2
}

// ================= MID path (round-4 proven, 471 us) =================
__global__ void pack_qw(const int* __restrict__ qw, unsigned int* __restrict__ qp) {
    int stride = gridDim.x * blockDim.x;
    for (int i = blockIdx.x * blockDim.x + threadIdx.x; i < N_DIM * KP; i += stride) {
        const int* src = qw + (size_t)i * 8;
        int4 a = *(const int4*)src;
        int4 b = *(const int4*)(src + 4);
        unsigned int w = (unsigned)a.x | ((unsigned)a.z << 4) | ((unsigned)b.x << 8) | ((unsigned)b.z << 12)
                       | ((unsigned)a.y << 16) | ((unsigned)a.w << 20) | ((unsigned)b.y << 24) | ((unsigned)b.w << 28);
        qp[i] = w;
    }
}

__device__ __forceinline__ uint4 dq8m(unsigned int w, f16x2 s2, f16x2 z2) {
    const f16x2 k1024 = {(_Float16)1024.0f, (_Float16)1024.0f};
    union { f16x2 h; unsigned int u; } p0, p1, p2, p3;
    p0.u = 0x64006400u | (w & 0x000F000Fu);
    p1.u = 0x64006400u | ((w >> 4)  & 0x000F000Fu);
    p2.u = 0x64006400u | ((w >> 8)  & 0x000F000Fu);
    p3.u = 0x64006400u | ((w >> 12) & 0x000F000Fu);
    union { f16x2 h2[4]; uint4 v; } r;
    r.h2[0] = (p0.h - k1024) * s2 + z2;
    r.h2[1] = (p1.h - k1024) * s2 + z2;
    r.h2[2] = (p2.h - k1024) * s2 + z2;
    r.h2[3] = (p3.h - k1024) * s2 + z2;
    return r.v;
}

__global__ __launch_bounds__(256, 3) void wq_gemm_packed(
    const uint4*  __restrict__ xw, const uint4* __restrict__ qp4,
    const float*  __restrict__ scales, const float* __restrict__ zeros,
    const float*  __restrict__ bias, float* __restrict__ out)
{
    __shared__ __align__(16) unsigned short As[128 * 64];
    __shared__ __align__(16) unsigned short Bs[128 * 64];
    const int tid = threadIdx.x, lane = tid & 63, wid = tid >> 6;
    const int wm = wid >> 1, wn = wid & 1, l15 = lane & 15, l4 = lane >> 4;
    const int m0 = blockIdx.y * 128, n0 = blockIdx.x * 128;
    const int brow = tid >> 1, bhalf = tid & 1;
    f32x4 acc[4][4] = {};
    for (int g = 0; g < 32; ++g) {
        float s = scales[(size_t)g * N_DIM + n0 + brow];
        float z = zeros [(size_t)g * N_DIM + n0 + brow];
        f16x2 s2 = {(_Float16)s, (_Float16)s};
        f16x2 z2 = {(_Float16)z, (_Float16)z};
        #pragma unroll
        for (int half = 0; half < 2; ++half) {
            const int kt = g * 2 + half;
            #pragma unroll
            for (int i = 0; i < 4; ++i) {
                int off16 = i * 256 + tid;
                int row = off16 >> 3, sl = off16 & 7;
                const uint4* gsrc = xw + (size_t)(m0 + row) * KP + kt * 8 + sl;
                __builtin_amdgcn_global_load_lds(
                    (const __attribute__((address_space(1))) unsigned int*)gsrc,
                    (__attribute__((address_space(3))) unsigned int*)((char*)As + off16 * 16),
                    16, 0, 0);
            }
            uint4 qword = qp4[(size_t)(n0 + brow) * 128 + kt * 2 + bhalf];
            #pragma unroll
            for (int j = 0; j < 4; ++j) {
                unsigned int w = (j == 0) ? qword.x : (j == 1) ? qword.y : (j == 2) ? qword.z : qword.w;
                int sl = (bhalf * 4 + j) ^ (brow & 7);
                *(uint4*)((char*)Bs + brow * 128 + sl * 16) = dq8m(w, s2, z2);
            }
            __syncthreads();
            #pragma unroll
            for (int ks = 0; ks < 2; ++ks) {
                f16x8 a[4], b[4];
                #pragma unroll
                for (int m = 0; m < 4; ++m) {
                    int row = wm * 64 + m * 16 + l15;
                    int sl  = (ks * 4 + l4) ^ (row & 7);
                    a[m] = *(const f16x8*)((char*)As + row * 128 + sl * 16);
                }
                #pragma unroll
                for (int n = 0; n < 4; ++n) {
                    int row = wn * 64 + n * 16 + l15;
                    int sl  = (ks * 4 + l4) ^ (row & 7);
                    b[n] = *(const f16x8*)((char*)Bs + row * 128 + sl * 16);
                }
                #pragma unroll
                for (int m = 0; m < 4; ++m)
                    #pragma unroll
                    for (int n = 0; n < 4; ++n)
                        MFMA16(acc[m][n], a[m], b[n]);
            }
            __syncthreads();
        }
    }
    #pragma unroll
    for (int n = 0; n < 4; ++n) {
        int col = n0 + wn * 64 + n * 16 + l15;
        float bv = bias[col];
        #pragma unroll
        for (int m = 0; m < 4; ++m) {
            int rbase = m0 + wm * 64 + m * 16 + l4 * 4;
            #pragma unroll
            for (int j = 0; j < 4; ++j)
                out[(size_t)(rbase + j) * N_DIM + col] = acc[m][n][j] + bv;
        }
    }
}

extern "C" void kernel_launch(void* const* d_in, const int* in_sizes, int n_in,
                              void* d_out, int out_size, void* d_ws, size_t ws_size,
                              hipStream_t stream) {
    const float* x  = (const float*)d_in[0];
    const int*   qw = (const int*)d_in[1];
    const float* sc = (const float*)d_in[2];
    const float* zr = (const float*)d_in[3];
    const float* bi = (const float*)d_in[4];
    float* o = (float*)d_out;

    if (ws_size >= FULL_NEEDED) {
        uint4* wf = (uint4*)d_ws;
        uint4* xw = (uint4*)((char*)d_ws + XW2_OFFSET);
        dq_w  <<<2048, 256, 0, stream>>>(qw, sc, zr, wf);
        cvt_x <<<2048, 256, 0, stream>>>(x, xw);
        wq_gemm_8ph<<<dim3(688), dim3(512), 0, stream>>>(xw, wf, bi, o);
    } else {
        unsigned int* qp = (unsigned int*)d_ws;
        uint4* xw = (uint4*)((char*)d_ws + XW_OFFSET);
        pack_qw<<<2048, 256, 0, stream>>>(qw, qp);
        cvt_x  <<<2048, 256, 0, stream>>>(x, xw);
        dim3 grid(N_DIM / 128, M_DIM / 128);
        wq_gemm_packed<<<grid, dim3(256), 0, stream>>>((const uint4*)xw, (const uint4*)qp, sc, zr, bi, o);
    }
}